// Round 16
// baseline (102.564 us; speedup 1.0000x reference)
//
#include <hip/hip_runtime.h>
#include <math.h>

// Tropical bottleneck network — fully fused (R14 geometry: 256 blocks x 1024
// threads, 4 batch cols/block), instruction-optimized inner loop:
//  - X read as wave-uniform ds_read_b128 (4 h8 per 8-k chunk), h2 pieces are
//    free sub-register extractions (LDS layout [k][4cols]).
//  - W-half broadcast via VOP3P op_sel inline asm: v_pk_add_f16 with
//    op_sel:[0,b] op_sel_hi:[1,b] adds W.half[b] to both packed cols — no
//    splat instructions. Inner loop = 1 packed VALU instr per (row,col,k).
// Weights pre-chunked Wc[K/8][R][8] f16 (one-time cvt), streamed from L2.

typedef _Float16 h2 __attribute__((ext_vector_type(2)));
typedef _Float16 h8 __attribute__((ext_vector_type(8)));

template<int M> __device__ __forceinline__ h2 rdv(h2 a, h2 b) {
    if constexpr (M) return __builtin_elementwise_max(a, b);
    else             return __builtin_elementwise_min(a, b);
}
// d = { x.lo + w.lo , x.hi + w.lo }
__device__ __forceinline__ h2 pkadd_b0(h2 x, h2 w) {
    h2 d;
    asm("v_pk_add_f16 %0, %1, %2 op_sel:[0,0] op_sel_hi:[1,0]"
        : "=v"(d) : "v"(x), "v"(w));
    return d;
}
// d = { x.lo + w.hi , x.hi + w.hi }
__device__ __forceinline__ h2 pkadd_b1(h2 x, h2 w) {
    h2 d;
    asm("v_pk_add_f16 %0, %1, %2 op_sel:[0,1] op_sel_hi:[1,1]"
        : "=v"(d) : "v"(x), "v"(w));
    return d;
}
#define XS(v, I0, I1) __builtin_shufflevector(v, v, I0, I1)

struct NetP {
    const float* x;
    const h8 *w11, *w12, *w21, *w22, *w31, *w32;
    const h8 *w41, *w42, *sw1, *sw2, *scw1, *scw2;
    const _Float16 *b12, *b22, *b32, *b42, *sb2, *scb2;
    float* out;
};

// One semiring stage on this block's 4 batch cols.
// X: LDS [K][4] halfs (h8 = 2 k x 4 cols). Y: LDS [R][4] (or global if GOUT).
template<int ISMAX, int R, int K, bool GOUT>
__device__ __forceinline__ void stage(
    const h8* __restrict__ Wc,          // global chunked [K/8][R]
    const _Float16* __restrict__ bias,  // global f16 (ISMAX) or nullptr
    const _Float16* __restrict__ X,
    const _Float16* __restrict__ E1,    // LDS min-combine or nullptr
    const _Float16* __restrict__ E2,    // LDS max-combine or nullptr
    _Float16* __restrict__ Y,
    float* __restrict__ gout, int b0,
    h2* __restrict__ part)
{
    constexpr int NRG = R / 2;               // row-groups (2 rows/thread)
    constexpr int KS  = 1024 / NRG;          // K-split ways (8 or 4)
    static_assert(NRG * KS == 1024, "thread mapping");
    const int tid  = threadIdx.x;
    const int rowg = tid & (NRG - 1);
    const int kq   = tid / NRG;              // wave-uniform
    const int r0 = rowg, r1 = rowg + NRG;
    constexpr int NC = (K / 8) / KS;         // chunks per thread
    const int kc0 = kq * NC;

    const h8* X8 = (const h8*)X;             // h8 = 2 k x 4 cols

#define RDA(a, b) rdv<ISMAX>((a), (b))
// one m-group: xm covers k=2m,2m+1 (4 cols); wa/wb = W VGPR m of rows r0/r1
#define MBODY(xm, w0_, w1_, M0, M1)                               \
    {   h2 wa = XS(w0_, M0, M1), wb = XS(w1_, M0, M1);            \
        a00 = RDA(a00, pkadd_b0(XS(xm, 0, 1), wa));               \
        a01 = RDA(a01, pkadd_b0(XS(xm, 2, 3), wa));               \
        a10 = RDA(a10, pkadd_b0(XS(xm, 0, 1), wb));               \
        a11 = RDA(a11, pkadd_b0(XS(xm, 2, 3), wb));               \
        a00 = RDA(a00, pkadd_b1(XS(xm, 4, 5), wa));               \
        a01 = RDA(a01, pkadd_b1(XS(xm, 6, 7), wa));               \
        a10 = RDA(a10, pkadd_b1(XS(xm, 4, 5), wb));               \
        a11 = RDA(a11, pkadd_b1(XS(xm, 6, 7), wb)); }

    h2 a00, a01, a10, a11;
    {   // peel first chunk (init with m=0/b0, accumulate the rest)
        const h8* xc = X8 + (size_t)kc0 * 4;
        h8 w0 = Wc[(size_t)kc0 * R + r0];
        h8 w1 = Wc[(size_t)kc0 * R + r1];
        h8 xm = xc[0];
        h2 wa = XS(w0, 0, 1), wb = XS(w1, 0, 1);
        a00 = pkadd_b0(XS(xm, 0, 1), wa);
        a01 = pkadd_b0(XS(xm, 2, 3), wa);
        a10 = pkadd_b0(XS(xm, 0, 1), wb);
        a11 = pkadd_b0(XS(xm, 2, 3), wb);
        a00 = RDA(a00, pkadd_b1(XS(xm, 4, 5), wa));
        a01 = RDA(a01, pkadd_b1(XS(xm, 6, 7), wa));
        a10 = RDA(a10, pkadd_b1(XS(xm, 4, 5), wb));
        a11 = RDA(a11, pkadd_b1(XS(xm, 6, 7), wb));
        xm = xc[1]; MBODY(xm, w0, w1, 2, 3);
        xm = xc[2]; MBODY(xm, w0, w1, 4, 5);
        xm = xc[3]; MBODY(xm, w0, w1, 6, 7);
    }
#pragma unroll 2
    for (int kc = kc0 + 1; kc < kc0 + NC; ++kc) {
        const h8* xc = X8 + (size_t)kc * 4;
        h8 w0 = Wc[(size_t)kc * R + r0];
        h8 w1 = Wc[(size_t)kc * R + r1];
        h8 xm;
        xm = xc[0]; MBODY(xm, w0, w1, 0, 1);
        xm = xc[1]; MBODY(xm, w0, w1, 2, 3);
        xm = xc[2]; MBODY(xm, w0, w1, 4, 5);
        xm = xc[3]; MBODY(xm, w0, w1, 6, 7);
    }
#undef MBODY

    if (kq) {
        h2* pp = part + (size_t)(kq - 1) * R * 2;
        pp[r0 * 2] = a00; pp[r0 * 2 + 1] = a01;
        pp[r1 * 2] = a10; pp[r1 * 2 + 1] = a11;
    }
    __syncthreads();
    if (kq == 0) {
#pragma unroll
        for (int qq = 0; qq < KS - 1; ++qq) {
            const h2* pp = part + (size_t)qq * R * 2;
            a00 = RDA(a00, pp[r0 * 2]); a01 = RDA(a01, pp[r0 * 2 + 1]);
            a10 = RDA(a10, pp[r1 * 2]); a11 = RDA(a11, pp[r1 * 2 + 1]);
        }
        if (ISMAX) {
            _Float16 q0 = bias[r0], q1 = bias[r1];
            h2 s0 = {q0, q0}, s1 = {q1, q1};
            a00 += s0; a01 += s0; a10 += s1; a11 += s1;
        }
        if (E1) {
            const h2* e = (const h2*)E1;
            a00 = __builtin_elementwise_min(a00, e[r0 * 2]);
            a01 = __builtin_elementwise_min(a01, e[r0 * 2 + 1]);
            a10 = __builtin_elementwise_min(a10, e[r1 * 2]);
            a11 = __builtin_elementwise_min(a11, e[r1 * 2 + 1]);
        }
        if (E2) {
            const h2* e = (const h2*)E2;
            a00 = __builtin_elementwise_max(a00, e[r0 * 2]);
            a01 = __builtin_elementwise_max(a01, e[r0 * 2 + 1]);
            a10 = __builtin_elementwise_max(a10, e[r1 * 2]);
            a11 = __builtin_elementwise_max(a11, e[r1 * 2 + 1]);
        }
        if constexpr (GOUT) {
            gout[(size_t)(b0 + 0) * 512 + r0] = (float)a00[0];
            gout[(size_t)(b0 + 1) * 512 + r0] = (float)a00[1];
            gout[(size_t)(b0 + 2) * 512 + r0] = (float)a01[0];
            gout[(size_t)(b0 + 3) * 512 + r0] = (float)a01[1];
            gout[(size_t)(b0 + 0) * 512 + r1] = (float)a10[0];
            gout[(size_t)(b0 + 1) * 512 + r1] = (float)a10[1];
            gout[(size_t)(b0 + 2) * 512 + r1] = (float)a11[0];
            gout[(size_t)(b0 + 3) * 512 + r1] = (float)a11[1];
        } else {
            h2* y = (h2*)Y;
            y[r0 * 2] = a00; y[r0 * 2 + 1] = a01;
            y[r1 * 2] = a10; y[r1 * 2 + 1] = a11;
        }
    }
#undef RDA
    __syncthreads();
}

__global__ __launch_bounds__(1024) void netf(NetP p)
{
    __shared__ __align__(16) _Float16 X0[256 * 4];               // 2 KB
    __shared__ __align__(16) _Float16 B0[512 * 4], B1[512 * 4];  // 4 KB each
    __shared__ __align__(16) _Float16 B2[512 * 4], B3[512 * 4];
    __shared__ __align__(16) h2 part[3584];                      // 14 KB
    const int tid = threadIdx.x;
    const int b0  = blockIdx.x * 4;

    {   // load x f32 -> X0 f16 [k][4b], one value per thread
        const int bl = tid >> 8;          // 0..3
        const int k  = tid & 255;
        X0[k * 4 + bl] = (_Float16)p.x[(size_t)(b0 + bl) * 256 + k];
    }
    __syncthreads();

    float* o = p.out;
    // bottleneck shortcut first (keeps X0 live only through layer 1)
    stage<0,512,256,false>(p.scw1, nullptr, X0, nullptr, nullptr, B0, o, b0, part);
    stage<1,512,512,false>(p.scw2, p.scb2,  B0, nullptr, nullptr, B1, o, b0, part); // B1=SCout
    // layer 1
    stage<0,256,256,false>(p.w11, nullptr, X0, nullptr, nullptr, B0, o, b0, part);
    stage<1,256,256,false>(p.w12, p.b12,   B0, X0,      nullptr, B2, o, b0, part);
    // layer 2
    stage<0,256,256,false>(p.w21, nullptr, B2, nullptr, nullptr, B0, o, b0, part);
    stage<1,256,256,false>(p.w22, p.b22,   B0, B2,      nullptr, B3, o, b0, part);
    // layer 3
    stage<0,256,256,false>(p.w31, nullptr, B3, nullptr, nullptr, B0, o, b0, part);
    stage<1,256,256,false>(p.w32, p.b32,   B0, B3,      nullptr, B2, o, b0, part);  // B2=x3
    // layer 4
    stage<0,512,256,false>(p.w41, nullptr, B2, nullptr, nullptr, B0, o, b0, part);  // T1
    stage<0,512,256,false>(p.sw1, nullptr, B2, nullptr, nullptr, B3, o, b0, part);  // T2
    stage<1,512,512,false>(p.w42, p.b42,   B0, nullptr, nullptr, B2, o, b0, part);  // O4
    // final: max(min(maxbplus(T2,sw2,sb2), O4), SCout) -> global out
    stage<1,512,512,true >(p.sw2, p.sb2,   B3, B2,      B1, nullptr, o, b0, part);
}

// ---- one-time prep: weights f32 [R][K] -> f16 chunked Wc[K/8][R][8]; biases ----
struct Prep {
    const float* s[12]; h8* d[12]; int R[12]; int K[12];
    const float* bs[6]; _Float16* bd[6]; int bn[6];
};
__global__ __launch_bounds__(256) void cvtw(Prep p)
{
    const int m = blockIdx.y;
    if (m == 12) {                        // bias slice
        if (blockIdx.x != 0) return;
        for (int s = 0; s < 6; ++s)
            for (int i = threadIdx.x; i < p.bn[s]; i += 256)
                p.bd[s][i] = (_Float16)p.bs[s][i];
        return;
    }
    const int R = p.R[m], K = p.K[m];
    const int tilesR = R >> 6;
    const int nt = tilesR * (K >> 6);
    const int t = blockIdx.x;
    if (t >= nt) return;
    const int tr = t % tilesR, tk = t / tilesR;

    __shared__ float s[64][65];
    const int lane = threadIdx.x & 63, ty = threadIdx.x >> 6;
    const float* src = p.s[m];
#pragma unroll
    for (int r = ty; r < 64; r += 4)
        s[r][lane] = src[(size_t)(tr * 64 + r) * K + tk * 64 + lane];
    __syncthreads();
    h8* dst = p.d[m];
#pragma unroll
    for (int c = 0; c < 2; ++c) {
        int cc = ty + c * 4;                 // 0..7
        h8 v;
#pragma unroll
        for (int j = 0; j < 8; ++j) v[j] = (_Float16)s[lane][cc * 8 + j];
        dst[(size_t)(tk * 8 + cc) * R + tr * 64 + lane] = v;
    }
}

extern "C" void kernel_launch(void* const* d_in, const int* in_sizes, int n_in,
                              void* d_out, int out_size, void* d_ws, size_t ws_size,
                              hipStream_t stream) {
    (void)in_sizes; (void)n_in; (void)ws_size; (void)out_size;
    const float* fin[19];
    for (int i = 0; i < 19; ++i) fin[i] = (const float*)d_in[i];

    _Float16* hw = (_Float16*)d_ws;

    _Float16* w11c  = hw;
    _Float16* w12c  = hw + 65536;
    _Float16* w21c  = hw + 131072;
    _Float16* w22c  = hw + 196608;
    _Float16* w31c  = hw + 262144;
    _Float16* w32c  = hw + 327680;
    _Float16* w41c  = hw + 393216;   // 131072
    _Float16* w42c  = hw + 524288;   // 262144
    _Float16* sw1c  = hw + 786432;   // 131072
    _Float16* sw2c  = hw + 917504;   // 262144
    _Float16* scw1c = hw + 1179648;  // 131072
    _Float16* scw2c = hw + 1310720;  // 262144
    _Float16* bia   = hw + 1572864;
    _Float16* b12 = bia, *b22 = bia + 256, *b32 = bia + 512;
    _Float16* b42 = bia + 768, *sb2 = bia + 1280, *scb2 = bia + 1792;

    Prep cw;
    const float* wsrc[12] = {fin[1], fin[2], fin[4], fin[5], fin[7], fin[8],
                             fin[10], fin[11], fin[13], fin[14], fin[16], fin[17]};
    _Float16* wdst[12]    = {w11c, w12c, w21c, w22c, w31c, w32c,
                             w41c, w42c, sw1c, sw2c, scw1c, scw2c};
    const int wR[12] = {256,256,256,256,256,256, 512,512,512,512,512,512};
    const int wK[12] = {256,256,256,256,256,256, 256,512,256,512,256,512};
    for (int i = 0; i < 12; ++i) {
        cw.s[i] = wsrc[i]; cw.d[i] = (h8*)wdst[i]; cw.R[i] = wR[i]; cw.K[i] = wK[i];
    }
    const float* bsrc[6] = {fin[3], fin[6], fin[9], fin[12], fin[15], fin[18]};
    _Float16* bdst[6]    = {b12, b22, b32, b42, sb2, scb2};
    const int bn[6]      = {256, 256, 256, 512, 512, 512};
    for (int i = 0; i < 6; ++i) { cw.bs[i] = bsrc[i]; cw.bd[i] = bdst[i]; cw.bn[i] = bn[i]; }

    NetP p;
    p.x   = fin[0];
    p.w11 = (const h8*)w11c; p.w12 = (const h8*)w12c;
    p.w21 = (const h8*)w21c; p.w22 = (const h8*)w22c;
    p.w31 = (const h8*)w31c; p.w32 = (const h8*)w32c;
    p.w41 = (const h8*)w41c; p.w42 = (const h8*)w42c;
    p.sw1 = (const h8*)sw1c; p.sw2 = (const h8*)sw2c;
    p.scw1 = (const h8*)scw1c; p.scw2 = (const h8*)scw2c;
    p.b12 = b12; p.b22 = b22; p.b32 = b32; p.b42 = b42; p.sb2 = sb2; p.scb2 = scb2;
    p.out = (float*)d_out;

    cvtw<<<dim3(64, 13), 256, 0, stream>>>(cw);
    netf<<<dim3(256), dim3(1024), 0, stream>>>(p);
}

// Round 17
// 82.463 us; speedup vs baseline: 1.2438x; 1.2438x over previous
//
#include <hip/hip_runtime.h>
#include <math.h>

// Tropical bottleneck network — fully fused, k-axis-packed f16 inner loop.
// 512 blocks x 512 threads; each block owns 2 batch cols, runs all 12 stages
// locally (LDS barriers). Activations in LDS, layout [col][k] (h8 = 8
// consecutive k of one col -> wave-uniform ds_read_b128 broadcast).
// Weights pre-chunked Wc[K/8][R][8] f16 (h8 = 8 k of one row), L2-resident.
// Accumulator h2 = {even-k, odd-k} partial reductions for one (row,col):
// both packed operands are natural h2s -> v_pk_add_f16 + v_pk_min/max_f16,
// 1 instr per (row,col,k) pair, NO splats, NO inline asm.
// 4 rows x 2 cols per thread; KS-way K-split (8 or 4) with pre-reduced
// scalar partials combined through LDS by kq==0.

typedef _Float16 h2 __attribute__((ext_vector_type(2)));
typedef _Float16 h8 __attribute__((ext_vector_type(8)));

template<int M, typename V> __device__ __forceinline__ V rdv(V a, V b) {
    if constexpr (M) return __builtin_elementwise_max(a, b);
    else             return __builtin_elementwise_min(a, b);
}
template<int M> __device__ __forceinline__ _Float16 rd1(_Float16 a, _Float16 b) {
    if constexpr (M) return a > b ? a : b;
    else             return a < b ? a : b;
}
#define XS(v, I0, I1) __builtin_shufflevector(v, v, I0, I1)

struct NetP {
    const float* x;
    const h8 *w11, *w12, *w21, *w22, *w31, *w32;
    const h8 *w41, *w42, *sw1, *sw2, *scw1, *scw2;
    const _Float16 *b12, *b22, *b32, *b42, *sb2, *scb2;
    float* out;
};

// One semiring stage on this block's 2 batch cols.
// X: LDS [2][K] halfs. Y: LDS [2][R] (or global f32 out if GOUT).
template<int ISMAX, int R, int K, bool GOUT>
__device__ __forceinline__ void stage(
    const h8* __restrict__ Wc,          // global chunked [K/8][R]
    const _Float16* __restrict__ bias,  // global f16 (ISMAX) or nullptr
    const _Float16* __restrict__ X,     // LDS [2][K]
    const _Float16* __restrict__ E1,    // LDS [2][R] min-combine or nullptr
    const _Float16* __restrict__ E2,    // LDS [2][R] max-combine or nullptr
    _Float16* __restrict__ Y,           // LDS [2][R]
    float* __restrict__ gout, int b0,
    _Float16* __restrict__ part)        // 16B-aligned scratch
{
    constexpr int NRG = R / 4;               // row-groups (4 rows/thread)
    constexpr int KS  = 512 / NRG;           // K-split ways (8 or 4)
    constexpr int NC  = (K / 8) / KS;        // chunks per thread
    static_assert(NRG * KS == 512, "thread mapping");
    const int tid  = threadIdx.x;
    const int rowg = tid & (NRG - 1);
    const int kq   = tid / NRG;              // wave-uniform
    const int kc0  = kq * NC;

    const h8* Xc0 = (const h8*)X + kc0;            // col 0
    const h8* Xc1 = (const h8*)(X + K) + kc0;      // col 1

    h2 a00, a01, a10, a11, a20, a21, a30, a31;     // [row i][col]

#define RDA(a, b) rdv<ISMAX>((a), (b))
#define PIECE(J0, J1)                                                   \
    {   h2 xa_ = XS(xa, J0, J1), xb_ = XS(xb, J0, J1); h2 t;            \
        t = XS(w0, J0, J1); a00 = RDA(a00, xa_ + t); a01 = RDA(a01, xb_ + t); \
        t = XS(w1, J0, J1); a10 = RDA(a10, xa_ + t); a11 = RDA(a11, xb_ + t); \
        t = XS(w2, J0, J1); a20 = RDA(a20, xa_ + t); a21 = RDA(a21, xb_ + t); \
        t = XS(w3, J0, J1); a30 = RDA(a30, xa_ + t); a31 = RDA(a31, xb_ + t); }

    {   // peel first chunk: piece 0 initializes (no +-INF)
        h8 xa = Xc0[0], xb = Xc1[0];
        const h8* Wr = Wc + (size_t)kc0 * R + rowg;
        h8 w0 = Wr[0], w1 = Wr[NRG], w2 = Wr[2 * NRG], w3 = Wr[3 * NRG];
        {   h2 xa_ = XS(xa, 0, 1), xb_ = XS(xb, 0, 1); h2 t;
            t = XS(w0, 0, 1); a00 = xa_ + t; a01 = xb_ + t;
            t = XS(w1, 0, 1); a10 = xa_ + t; a11 = xb_ + t;
            t = XS(w2, 0, 1); a20 = xa_ + t; a21 = xb_ + t;
            t = XS(w3, 0, 1); a30 = xa_ + t; a31 = xb_ + t;
        }
        PIECE(2, 3) PIECE(4, 5) PIECE(6, 7)
    }
#pragma unroll 2
    for (int kc = 1; kc < NC; ++kc) {
        h8 xa = Xc0[kc], xb = Xc1[kc];
        const h8* Wr = Wc + (size_t)(kc0 + kc) * R + rowg;
        h8 w0 = Wr[0], w1 = Wr[NRG], w2 = Wr[2 * NRG], w3 = Wr[3 * NRG];
        PIECE(0, 1) PIECE(2, 3) PIECE(4, 5) PIECE(6, 7)
    }
#undef PIECE

    // pre-reduce even/odd k-slots -> 8 scalars, packed as one h8
    h8 v8;
    v8[0] = rd1<ISMAX>(a00[0], a00[1]); v8[1] = rd1<ISMAX>(a01[0], a01[1]);
    v8[2] = rd1<ISMAX>(a10[0], a10[1]); v8[3] = rd1<ISMAX>(a11[0], a11[1]);
    v8[4] = rd1<ISMAX>(a20[0], a20[1]); v8[5] = rd1<ISMAX>(a21[0], a21[1]);
    v8[6] = rd1<ISMAX>(a30[0], a30[1]); v8[7] = rd1<ISMAX>(a31[0], a31[1]);

    if (kq) *(h8*)(part + ((size_t)(kq - 1) * NRG + rowg) * 8) = v8;
    __syncthreads();
    if (kq == 0) {
#pragma unroll
        for (int qq = 0; qq < KS - 1; ++qq)
            v8 = rdv<ISMAX>(v8, *(const h8*)(part + ((size_t)qq * NRG + rowg) * 8));

#pragma unroll
        for (int i = 0; i < 4; ++i) {
            const int r = rowg + i * NRG;
            _Float16 oc0 = v8[2 * i], oc1 = v8[2 * i + 1];
            if (ISMAX) { _Float16 bi = bias[r]; oc0 += bi; oc1 += bi; }
            if (E1) {
                _Float16 e0 = E1[r], e1 = E1[R + r];
                oc0 = oc0 < e0 ? oc0 : e0; oc1 = oc1 < e1 ? oc1 : e1;
            }
            if (E2) {
                _Float16 e0 = E2[r], e1 = E2[R + r];
                oc0 = oc0 > e0 ? oc0 : e0; oc1 = oc1 > e1 ? oc1 : e1;
            }
            if constexpr (GOUT) {
                gout[(size_t)(b0 + 0) * 512 + r] = (float)oc0;
                gout[(size_t)(b0 + 1) * 512 + r] = (float)oc1;
            } else {
                Y[r] = oc0; Y[R + r] = oc1;
            }
        }
    }
#undef RDA
    __syncthreads();
}

__global__ __launch_bounds__(512) void netf(NetP p)
{
    __shared__ __align__(16) _Float16 X0[2 * 256];               // 1 KB
    __shared__ __align__(16) _Float16 B0[2 * 512], B1[2 * 512];  // 2 KB each
    __shared__ __align__(16) _Float16 B2[2 * 512], B3[2 * 512];
    __shared__ __align__(16) _Float16 part[3584];                // 7 KB
    const int tid = threadIdx.x;
    const int b0  = blockIdx.x * 2;

    {   // x f32 -> X0 f16, layout [col][k]
        const int bl = tid >> 8;          // 0..1
        const int k  = tid & 255;
        X0[bl * 256 + k] = (_Float16)p.x[(size_t)(b0 + bl) * 256 + k];
    }
    __syncthreads();

    float* o = p.out;
    // bottleneck shortcut first (keeps X0 live only through layer 1)
    stage<0,512,256,false>(p.scw1, nullptr, X0, nullptr, nullptr, B0, o, b0, part);
    stage<1,512,512,false>(p.scw2, p.scb2,  B0, nullptr, nullptr, B1, o, b0, part); // B1=SCout
    // layer 1
    stage<0,256,256,false>(p.w11, nullptr, X0, nullptr, nullptr, B0, o, b0, part);
    stage<1,256,256,false>(p.w12, p.b12,   B0, X0,      nullptr, B2, o, b0, part);
    // layer 2
    stage<0,256,256,false>(p.w21, nullptr, B2, nullptr, nullptr, B0, o, b0, part);
    stage<1,256,256,false>(p.w22, p.b22,   B0, B2,      nullptr, B3, o, b0, part);
    // layer 3
    stage<0,256,256,false>(p.w31, nullptr, B3, nullptr, nullptr, B0, o, b0, part);
    stage<1,256,256,false>(p.w32, p.b32,   B0, B3,      nullptr, B2, o, b0, part);  // B2=x3
    // layer 4
    stage<0,512,256,false>(p.w41, nullptr, B2, nullptr, nullptr, B0, o, b0, part);  // T1
    stage<0,512,256,false>(p.sw1, nullptr, B2, nullptr, nullptr, B3, o, b0, part);  // T2
    stage<1,512,512,false>(p.w42, p.b42,   B0, nullptr, nullptr, B2, o, b0, part);  // O4
    // final: max(min(maxbplus(T2,sw2,sb2), O4), SCout) -> global out
    stage<1,512,512,true >(p.sw2, p.sb2,   B3, B2,      B1, nullptr, o, b0, part);
}

// ---- one-time prep: weights f32 [R][K] -> f16 chunked Wc[K/8][R][8]; biases ----
struct Prep {
    const float* s[12]; h8* d[12]; int R[12]; int K[12];
    const float* bs[6]; _Float16* bd[6]; int bn[6];
};
__global__ __launch_bounds__(256) void cvtw(Prep p)
{
    const int m = blockIdx.y;
    if (m == 12) {                        // bias slice
        if (blockIdx.x != 0) return;
        for (int s = 0; s < 6; ++s)
            for (int i = threadIdx.x; i < p.bn[s]; i += 256)
                p.bd[s][i] = (_Float16)p.bs[s][i];
        return;
    }
    const int R = p.R[m], K = p.K[m];
    const int tilesR = R >> 6;
    const int nt = tilesR * (K >> 6);
    const int t = blockIdx.x;
    if (t >= nt) return;
    const int tr = t % tilesR, tk = t / tilesR;

    __shared__ float s[64][65];
    const int lane = threadIdx.x & 63, ty = threadIdx.x >> 6;
    const float* src = p.s[m];
#pragma unroll
    for (int r = ty; r < 64; r += 4)
        s[r][lane] = src[(size_t)(tr * 64 + r) * K + tk * 64 + lane];
    __syncthreads();
    h8* dst = p.d[m];
#pragma unroll
    for (int c = 0; c < 2; ++c) {
        int cc = ty + c * 4;                 // 0..7
        h8 v;
#pragma unroll
        for (int j = 0; j < 8; ++j) v[j] = (_Float16)s[lane][cc * 8 + j];
        dst[(size_t)(tk * 8 + cc) * R + tr * 64 + lane] = v;
    }
}

extern "C" void kernel_launch(void* const* d_in, const int* in_sizes, int n_in,
                              void* d_out, int out_size, void* d_ws, size_t ws_size,
                              hipStream_t stream) {
    (void)in_sizes; (void)n_in; (void)ws_size; (void)out_size;
    const float* fin[19];
    for (int i = 0; i < 19; ++i) fin[i] = (const float*)d_in[i];

    _Float16* hw = (_Float16*)d_ws;

    _Float16* w11c  = hw;
    _Float16* w12c  = hw + 65536;
    _Float16* w21c  = hw + 131072;
    _Float16* w22c  = hw + 196608;
    _Float16* w31c  = hw + 262144;
    _Float16* w32c  = hw + 327680;
    _Float16* w41c  = hw + 393216;   // 131072
    _Float16* w42c  = hw + 524288;   // 262144
    _Float16* sw1c  = hw + 786432;   // 131072
    _Float16* sw2c  = hw + 917504;   // 262144
    _Float16* scw1c = hw + 1179648;  // 131072
    _Float16* scw2c = hw + 1310720;  // 262144
    _Float16* bia   = hw + 1572864;
    _Float16* b12 = bia, *b22 = bia + 256, *b32 = bia + 512;
    _Float16* b42 = bia + 768, *sb2 = bia + 1280, *scb2 = bia + 1792;

    Prep cw;
    const float* wsrc[12] = {fin[1], fin[2], fin[4], fin[5], fin[7], fin[8],
                             fin[10], fin[11], fin[13], fin[14], fin[16], fin[17]};
    _Float16* wdst[12]    = {w11c, w12c, w21c, w22c, w31c, w32c,
                             w41c, w42c, sw1c, sw2c, scw1c, scw2c};
    const int wR[12] = {256,256,256,256,256,256, 512,512,512,512,512,512};
    const int wK[12] = {256,256,256,256,256,256, 256,512,256,512,256,512};
    for (int i = 0; i < 12; ++i) {
        cw.s[i] = wsrc[i]; cw.d[i] = (h8*)wdst[i]; cw.R[i] = wR[i]; cw.K[i] = wK[i];
    }
    const float* bsrc[6] = {fin[3], fin[6], fin[9], fin[12], fin[15], fin[18]};
    _Float16* bdst[6]    = {b12, b22, b32, b42, sb2, scb2};
    const int bn[6]      = {256, 256, 256, 512, 512, 512};
    for (int i = 0; i < 6; ++i) { cw.bs[i] = bsrc[i]; cw.bd[i] = bdst[i]; cw.bn[i] = bn[i]; }

    NetP p;
    p.x   = fin[0];
    p.w11 = (const h8*)w11c; p.w12 = (const h8*)w12c;
    p.w21 = (const h8*)w21c; p.w22 = (const h8*)w22c;
    p.w31 = (const h8*)w31c; p.w32 = (const h8*)w32c;
    p.w41 = (const h8*)w41c; p.w42 = (const h8*)w42c;
    p.sw1 = (const h8*)sw1c; p.sw2 = (const h8*)sw2c;
    p.scw1 = (const h8*)scw1c; p.scw2 = (const h8*)scw2c;
    p.b12 = b12; p.b22 = b22; p.b32 = b32; p.b42 = b42; p.sb2 = sb2; p.scb2 = scb2;
    p.out = (float*)d_out;

    cvtw<<<dim3(64, 13), 256, 0, stream>>>(cw);
    netf<<<dim3(512), dim3(512), 0, stream>>>(p);
}

// Round 18
// 79.947 us; speedup vs baseline: 1.2829x; 1.0315x over previous
//
#include <hip/hip_runtime.h>
#include <math.h>

// Tropical bottleneck network — fully fused, k-axis-packed f16 inner loop
// (R17 structure), with the inner-loop arithmetic forced to packed VOP3P via
// plain inline asm (v_pk_add_f16 / v_pk_min_f16 / v_pk_max_f16, no modifiers).
// Rationale: measured VALUBusy on R14/R17 matches a "v2f16 scalarized" model
// (~2x core instrs); plain-mnemonic asm pins the packed encoding while
// keeping operands as naturally aligned h2 sub-registers (no shuffles).

typedef _Float16 h2 __attribute__((ext_vector_type(2)));
typedef _Float16 h8 __attribute__((ext_vector_type(8)));

template<int M, typename V> __device__ __forceinline__ V rdv(V a, V b) {
    if constexpr (M) return __builtin_elementwise_max(a, b);
    else             return __builtin_elementwise_min(a, b);
}
template<int M> __device__ __forceinline__ _Float16 rd1(_Float16 a, _Float16 b) {
    if constexpr (M) return a > b ? a : b;
    else             return a < b ? a : b;
}
__device__ __forceinline__ h2 pk_add(h2 a, h2 b) {
    h2 d; asm("v_pk_add_f16 %0, %1, %2" : "=v"(d) : "v"(a), "v"(b)); return d;
}
template<int M> __device__ __forceinline__ h2 pk_red(h2 a, h2 b) {
    h2 d;
    if constexpr (M) asm("v_pk_max_f16 %0, %1, %2" : "=v"(d) : "v"(a), "v"(b));
    else             asm("v_pk_min_f16 %0, %1, %2" : "=v"(d) : "v"(a), "v"(b));
    return d;
}
#define XS(v, I0, I1) __builtin_shufflevector(v, v, I0, I1)

struct NetP {
    const float* x;
    const h8 *w11, *w12, *w21, *w22, *w31, *w32;
    const h8 *w41, *w42, *sw1, *sw2, *scw1, *scw2;
    const _Float16 *b12, *b22, *b32, *b42, *sb2, *scb2;
    float* out;
};

// One semiring stage on this block's 2 batch cols.
// X: LDS [2][K] halfs. Y: LDS [2][R] (or global f32 out if GOUT).
template<int ISMAX, int R, int K, bool GOUT>
__device__ __forceinline__ void stage(
    const h8* __restrict__ Wc,          // global chunked [K/8][R]
    const _Float16* __restrict__ bias,  // global f16 (ISMAX) or nullptr
    const _Float16* __restrict__ X,     // LDS [2][K]
    const _Float16* __restrict__ E1,    // LDS [2][R] min-combine or nullptr
    const _Float16* __restrict__ E2,    // LDS [2][R] max-combine or nullptr
    _Float16* __restrict__ Y,           // LDS [2][R]
    float* __restrict__ gout, int b0,
    _Float16* __restrict__ part)        // 16B-aligned scratch
{
    constexpr int NRG = R / 4;               // row-groups (4 rows/thread)
    constexpr int KS  = 512 / NRG;           // K-split ways (8 or 4)
    constexpr int NC  = (K / 8) / KS;        // chunks per thread
    static_assert(NRG * KS == 512, "thread mapping");
    const int tid  = threadIdx.x;
    const int rowg = tid & (NRG - 1);
    const int kq   = tid / NRG;              // wave-uniform
    const int kc0  = kq * NC;

    const h8* Xc0 = (const h8*)X + kc0;            // col 0
    const h8* Xc1 = (const h8*)(X + K) + kc0;      // col 1

    h2 a00, a01, a10, a11, a20, a21, a30, a31;     // [row i][col]

#define PIECE(J0, J1)                                                   \
    {   h2 xa_ = XS(xa, J0, J1), xb_ = XS(xb, J0, J1); h2 t;            \
        t = XS(w0, J0, J1);                                             \
        a00 = pk_red<ISMAX>(a00, pk_add(xa_, t));                       \
        a01 = pk_red<ISMAX>(a01, pk_add(xb_, t));                       \
        t = XS(w1, J0, J1);                                             \
        a10 = pk_red<ISMAX>(a10, pk_add(xa_, t));                       \
        a11 = pk_red<ISMAX>(a11, pk_add(xb_, t));                       \
        t = XS(w2, J0, J1);                                             \
        a20 = pk_red<ISMAX>(a20, pk_add(xa_, t));                       \
        a21 = pk_red<ISMAX>(a21, pk_add(xb_, t));                       \
        t = XS(w3, J0, J1);                                             \
        a30 = pk_red<ISMAX>(a30, pk_add(xa_, t));                       \
        a31 = pk_red<ISMAX>(a31, pk_add(xb_, t)); }

    {   // peel first chunk: piece 0 initializes (no +-INF)
        h8 xa = Xc0[0], xb = Xc1[0];
        const h8* Wr = Wc + (size_t)kc0 * R + rowg;
        h8 w0 = Wr[0], w1 = Wr[NRG], w2 = Wr[2 * NRG], w3 = Wr[3 * NRG];
        {   h2 xa_ = XS(xa, 0, 1), xb_ = XS(xb, 0, 1); h2 t;
            t = XS(w0, 0, 1); a00 = pk_add(xa_, t); a01 = pk_add(xb_, t);
            t = XS(w1, 0, 1); a10 = pk_add(xa_, t); a11 = pk_add(xb_, t);
            t = XS(w2, 0, 1); a20 = pk_add(xa_, t); a21 = pk_add(xb_, t);
            t = XS(w3, 0, 1); a30 = pk_add(xa_, t); a31 = pk_add(xb_, t);
        }
        PIECE(2, 3) PIECE(4, 5) PIECE(6, 7)
    }
#pragma unroll 2
    for (int kc = 1; kc < NC; ++kc) {
        h8 xa = Xc0[kc], xb = Xc1[kc];
        const h8* Wr = Wc + (size_t)(kc0 + kc) * R + rowg;
        h8 w0 = Wr[0], w1 = Wr[NRG], w2 = Wr[2 * NRG], w3 = Wr[3 * NRG];
        PIECE(0, 1) PIECE(2, 3) PIECE(4, 5) PIECE(6, 7)
    }
#undef PIECE

    // pre-reduce even/odd k-slots -> 8 scalars, packed as one h8
    h8 v8;
    v8[0] = rd1<ISMAX>(a00[0], a00[1]); v8[1] = rd1<ISMAX>(a01[0], a01[1]);
    v8[2] = rd1<ISMAX>(a10[0], a10[1]); v8[3] = rd1<ISMAX>(a11[0], a11[1]);
    v8[4] = rd1<ISMAX>(a20[0], a20[1]); v8[5] = rd1<ISMAX>(a21[0], a21[1]);
    v8[6] = rd1<ISMAX>(a30[0], a30[1]); v8[7] = rd1<ISMAX>(a31[0], a31[1]);

    if (kq) *(h8*)(part + ((size_t)(kq - 1) * NRG + rowg) * 8) = v8;
    __syncthreads();
    if (kq == 0) {
#pragma unroll
        for (int qq = 0; qq < KS - 1; ++qq)
            v8 = rdv<ISMAX>(v8, *(const h8*)(part + ((size_t)qq * NRG + rowg) * 8));

#pragma unroll
        for (int i = 0; i < 4; ++i) {
            const int r = rowg + i * NRG;
            _Float16 oc0 = v8[2 * i], oc1 = v8[2 * i + 1];
            if (ISMAX) { _Float16 bi = bias[r]; oc0 += bi; oc1 += bi; }
            if (E1) {
                _Float16 e0 = E1[r], e1 = E1[R + r];
                oc0 = oc0 < e0 ? oc0 : e0; oc1 = oc1 < e1 ? oc1 : e1;
            }
            if (E2) {
                _Float16 e0 = E2[r], e1 = E2[R + r];
                oc0 = oc0 > e0 ? oc0 : e0; oc1 = oc1 > e1 ? oc1 : e1;
            }
            if constexpr (GOUT) {
                gout[(size_t)(b0 + 0) * 512 + r] = (float)oc0;
                gout[(size_t)(b0 + 1) * 512 + r] = (float)oc1;
            } else {
                Y[r] = oc0; Y[R + r] = oc1;
            }
        }
    }
    __syncthreads();
}

__global__ __launch_bounds__(512) void netf(NetP p)
{
    __shared__ __align__(16) _Float16 X0[2 * 256];               // 1 KB
    __shared__ __align__(16) _Float16 B0[2 * 512], B1[2 * 512];  // 2 KB each
    __shared__ __align__(16) _Float16 B2[2 * 512], B3[2 * 512];
    __shared__ __align__(16) _Float16 part[3584];                // 7 KB
    const int tid = threadIdx.x;
    const int b0  = blockIdx.x * 2;

    {   // x f32 -> X0 f16, layout [col][k]
        const int bl = tid >> 8;          // 0..1
        const int k  = tid & 255;
        X0[bl * 256 + k] = (_Float16)p.x[(size_t)(b0 + bl) * 256 + k];
    }
    __syncthreads();

    float* o = p.out;
    // bottleneck shortcut first (keeps X0 live only through layer 1)
    stage<0,512,256,false>(p.scw1, nullptr, X0, nullptr, nullptr, B0, o, b0, part);
    stage<1,512,512,false>(p.scw2, p.scb2,  B0, nullptr, nullptr, B1, o, b0, part); // B1=SCout
    // layer 1
    stage<0,256,256,false>(p.w11, nullptr, X0, nullptr, nullptr, B0, o, b0, part);
    stage<1,256,256,false>(p.w12, p.b12,   B0, X0,      nullptr, B2, o, b0, part);
    // layer 2
    stage<0,256,256,false>(p.w21, nullptr, B2, nullptr, nullptr, B0, o, b0, part);
    stage<1,256,256,false>(p.w22, p.b22,   B0, B2,      nullptr, B3, o, b0, part);
    // layer 3
    stage<0,256,256,false>(p.w31, nullptr, B3, nullptr, nullptr, B0, o, b0, part);
    stage<1,256,256,false>(p.w32, p.b32,   B0, B3,      nullptr, B2, o, b0, part);  // B2=x3
    // layer 4
    stage<0,512,256,false>(p.w41, nullptr, B2, nullptr, nullptr, B0, o, b0, part);  // T1
    stage<0,512,256,false>(p.sw1, nullptr, B2, nullptr, nullptr, B3, o, b0, part);  // T2
    stage<1,512,512,false>(p.w42, p.b42,   B0, nullptr, nullptr, B2, o, b0, part);  // O4
    // final: max(min(maxbplus(T2,sw2,sb2), O4), SCout) -> global out
    stage<1,512,512,true >(p.sw2, p.sb2,   B3, B2,      B1, nullptr, o, b0, part);
}

// ---- one-time prep: weights f32 [R][K] -> f16 chunked Wc[K/8][R][8]; biases ----
struct Prep {
    const float* s[12]; h8* d[12]; int R[12]; int K[12];
    const float* bs[6]; _Float16* bd[6]; int bn[6];
};
__global__ __launch_bounds__(256) void cvtw(Prep p)
{
    const int m = blockIdx.y;
    if (m == 12) {                        // bias slice
        if (blockIdx.x != 0) return;
        for (int s = 0; s < 6; ++s)
            for (int i = threadIdx.x; i < p.bn[s]; i += 256)
                p.bd[s][i] = (_Float16)p.bs[s][i];
        return;
    }
    const int R = p.R[m], K = p.K[m];
    const int tilesR = R >> 6;
    const int nt = tilesR * (K >> 6);
    const int t = blockIdx.x;
    if (t >= nt) return;
    const int tr = t % tilesR, tk = t / tilesR;

    __shared__ float s[64][65];
    const int lane = threadIdx.x & 63, ty = threadIdx.x >> 6;
    const float* src = p.s[m];
#pragma unroll
    for (int r = ty; r < 64; r += 4)
        s[r][lane] = src[(size_t)(tr * 64 + r) * K + tk * 64 + lane];
    __syncthreads();
    h8* dst = p.d[m];
#pragma unroll
    for (int c = 0; c < 2; ++c) {
        int cc = ty + c * 4;                 // 0..7
        h8 v;
#pragma unroll
        for (int j = 0; j < 8; ++j) v[j] = (_Float16)s[lane][cc * 8 + j];
        dst[(size_t)(tk * 8 + cc) * R + tr * 64 + lane] = v;
    }
}

extern "C" void kernel_launch(void* const* d_in, const int* in_sizes, int n_in,
                              void* d_out, int out_size, void* d_ws, size_t ws_size,
                              hipStream_t stream) {
    (void)in_sizes; (void)n_in; (void)ws_size; (void)out_size;
    const float* fin[19];
    for (int i = 0; i < 19; ++i) fin[i] = (const float*)d_in[i];

    _Float16* hw = (_Float16*)d_ws;

    _Float16* w11c  = hw;
    _Float16* w12c  = hw + 65536;
    _Float16* w21c  = hw + 131072;
    _Float16* w22c  = hw + 196608;
    _Float16* w31c  = hw + 262144;
    _Float16* w32c  = hw + 327680;
    _Float16* w41c  = hw + 393216;   // 131072
    _Float16* w42c  = hw + 524288;   // 262144
    _Float16* sw1c  = hw + 786432;   // 131072
    _Float16* sw2c  = hw + 917504;   // 262144
    _Float16* scw1c = hw + 1179648;  // 131072
    _Float16* scw2c = hw + 1310720;  // 262144
    _Float16* bia   = hw + 1572864;
    _Float16* b12 = bia, *b22 = bia + 256, *b32 = bia + 512;
    _Float16* b42 = bia + 768, *sb2 = bia + 1280, *scb2 = bia + 1792;

    Prep cw;
    const float* wsrc[12] = {fin[1], fin[2], fin[4], fin[5], fin[7], fin[8],
                             fin[10], fin[11], fin[13], fin[14], fin[16], fin[17]};
    _Float16* wdst[12]    = {w11c, w12c, w21c, w22c, w31c, w32c,
                             w41c, w42c, sw1c, sw2c, scw1c, scw2c};
    const int wR[12] = {256,256,256,256,256,256, 512,512,512,512,512,512};
    const int wK[12] = {256,256,256,256,256,256, 256,512,256,512,256,512};
    for (int i = 0; i < 12; ++i) {
        cw.s[i] = wsrc[i]; cw.d[i] = (h8*)wdst[i]; cw.R[i] = wR[i]; cw.K[i] = wK[i];
    }
    const float* bsrc[6] = {fin[3], fin[6], fin[9], fin[12], fin[15], fin[18]};
    _Float16* bdst[6]    = {b12, b22, b32, b42, sb2, scb2};
    const int bn[6]      = {256, 256, 256, 512, 512, 512};
    for (int i = 0; i < 6; ++i) { cw.bs[i] = bsrc[i]; cw.bd[i] = bdst[i]; cw.bn[i] = bn[i]; }

    NetP p;
    p.x   = fin[0];
    p.w11 = (const h8*)w11c; p.w12 = (const h8*)w12c;
    p.w21 = (const h8*)w21c; p.w22 = (const h8*)w22c;
    p.w31 = (const h8*)w31c; p.w32 = (const h8*)w32c;
    p.w41 = (const h8*)w41c; p.w42 = (const h8*)w42c;
    p.sw1 = (const h8*)sw1c; p.sw2 = (const h8*)sw2c;
    p.scw1 = (const h8*)scw1c; p.scw2 = (const h8*)scw2c;
    p.b12 = b12; p.b22 = b22; p.b32 = b32; p.b42 = b42; p.sb2 = sb2; p.scb2 = scb2;
    p.out = (float*)d_out;

    cvtw<<<dim3(64, 13), 256, 0, stream>>>(cw);
    netf<<<dim3(512), dim3(512), 0, stream>>>(p);
}